// Round 1
// baseline (493.305 us; speedup 1.0000x reference)
//
#include <hip/hip_runtime.h>
#include <math.h>

// Problem constants (B=16, T=2048, D=64, K=8192)
#define N_ROWS 32768
#define KCODES 8192
#define DDIM 64
#define SPLITK 4
#define KPER (KCODES / SPLITK)   // 2048 codes per split-k block
#define TM 128                    // rows per block
#define TKT 128                   // codes per LDS tile
#define NTILES (KPER / TKT)       // 16
#define LDSX 132                  // padded leading dim (row index stride)
#define LDSE 132

// ws layout (floats):
//   [0, KCODES)                     e2  (codebook squared norms)
//   [KCODES, KCODES+N_ROWS)         x2  (row squared norms)
//   [KCODES+N_ROWS, ... +N*SPLITK*2) partial (val, idx) pairs  -> total ~1.2 MB

// --- kernel 1: squared norms, replicating numpy pairwise-sum (n=64, 8 accumulators,
// square rounded separately from add => contraction OFF) ---
__global__ __launch_bounds__(256) void sumsq_kernel(const float* __restrict__ x,
                                                    const float* __restrict__ cb,
                                                    float* __restrict__ ws) {
#pragma clang fp contract(off)
    int t = blockIdx.x * 256 + threadIdx.x;  // grid covers exactly KCODES + N_ROWS
    const float* src;
    float* dst;
    if (t < KCODES) {
        src = cb + (size_t)t * DDIM;
        dst = ws + t;
    } else {
        int r = t - KCODES;
        src = x + (size_t)r * DDIM;
        dst = ws + KCODES + r;
    }
    float acc[8];
#pragma unroll
    for (int j = 0; j < 8; ++j) {
        float v = src[j];
        acc[j] = v * v;
    }
#pragma unroll
    for (int i = 8; i < 64; i += 8) {
#pragma unroll
        for (int j = 0; j < 8; ++j) {
            float v = src[i + j];
            acc[j] = acc[j] + v * v;
        }
    }
    *dst = ((acc[0] + acc[1]) + (acc[2] + acc[3])) + ((acc[4] + acc[5]) + (acc[6] + acc[7]));
}

// --- kernel 2: fused SGEMM-like distance + running argmin ---
// dist = (x2[r] + e2[k]) - 2*xe  computed exactly as numpy (fma(-2, xe, t) == t - 2*xe,
// since 2*xe is exact). xe accumulated as sequential fp32 fma over d (BLAS order).
__global__ __launch_bounds__(256) void dist_argmin_kernel(const float* __restrict__ x,
                                                          const float* __restrict__ cb,
                                                          const float* __restrict__ e2g,
                                                          const float* __restrict__ x2g,
                                                          float2* __restrict__ partial) {
    __shared__ float smem[DDIM * LDSX + DDIM * LDSE];  // 67584 B -> 2 blocks/CU
    float* Xs = smem;                 // Xs[d][r] at d*LDSX + r
    float* Es = smem + DDIM * LDSX;   // Es[d][c] at d*LDSE + c

    const int tid = threadIdx.x;
    const int bx = blockIdx.x;   // row block
    const int kz = blockIdx.y;   // split-k block
    const int row0 = bx * TM;
    const int code0 = kz * KPER;
    const int tr = tid >> 4;     // 0..15: row group (8 rows)
    const int tc = tid & 15;     // 0..15: code group (8 codes)

    // stage X tile (transposed) once: 128 rows x 64 d
    for (int i = tid; i < TM * 16; i += 256) {
        int r = i >> 4, q = i & 15;
        float4 v = ((const float4*)(x + (size_t)(row0 + r) * DDIM))[q];
        Xs[(4 * q + 0) * LDSX + r] = v.x;
        Xs[(4 * q + 1) * LDSX + r] = v.y;
        Xs[(4 * q + 2) * LDSX + r] = v.z;
        Xs[(4 * q + 3) * LDSX + r] = v.w;
    }

    float x2v[8];
#pragma unroll
    for (int j = 0; j < 8; ++j) x2v[j] = x2g[row0 + tr * 8 + j];

    float bestV[8];
    int bestI[8];
#pragma unroll
    for (int j = 0; j < 8; ++j) {
        bestV[j] = 3.0e38f;
        bestI[j] = 0;
    }

    for (int t = 0; t < NTILES; ++t) {
        __syncthreads();  // protect previous tile's reads before overwrite
        const int cbase = code0 + t * TKT;
        for (int i = tid; i < TKT * 16; i += 256) {
            int c = i >> 4, q = i & 15;
            float4 v = ((const float4*)(cb + (size_t)(cbase + c) * DDIM))[q];
            Es[(4 * q + 0) * LDSE + c] = v.x;
            Es[(4 * q + 1) * LDSE + c] = v.y;
            Es[(4 * q + 2) * LDSE + c] = v.z;
            Es[(4 * q + 3) * LDSE + c] = v.w;
        }
        __syncthreads();

        float acc[8][8];
#pragma unroll
        for (int a = 0; a < 8; ++a)
#pragma unroll
            for (int b = 0; b < 8; ++b) acc[a][b] = 0.0f;

#pragma unroll 4
        for (int d = 0; d < DDIM; ++d) {
            float xv[8], ev[8];
            float4 xa = *(const float4*)&Xs[d * LDSX + tr * 8];
            float4 xb = *(const float4*)&Xs[d * LDSX + tr * 8 + 4];
            float4 ea = *(const float4*)&Es[d * LDSE + tc * 8];
            float4 eb = *(const float4*)&Es[d * LDSE + tc * 8 + 4];
            xv[0] = xa.x; xv[1] = xa.y; xv[2] = xa.z; xv[3] = xa.w;
            xv[4] = xb.x; xv[5] = xb.y; xv[6] = xb.z; xv[7] = xb.w;
            ev[0] = ea.x; ev[1] = ea.y; ev[2] = ea.z; ev[3] = ea.w;
            ev[4] = eb.x; ev[5] = eb.y; ev[6] = eb.z; ev[7] = eb.w;
#pragma unroll
            for (int a = 0; a < 8; ++a)
#pragma unroll
                for (int b = 0; b < 8; ++b) acc[a][b] = fmaf(xv[a], ev[b], acc[a][b]);
        }

        // score + running argmin (codes ascending within thread => '<' keeps lowest idx)
#pragma unroll
        for (int b = 0; b < 8; ++b) {
            int ci = cbase + tc * 8 + b;
            float e2 = e2g[ci];
#pragma unroll
            for (int a = 0; a < 8; ++a) {
                float ts = x2v[a] + e2;
                float dist = fmaf(-2.0f, acc[a][b], ts);
                if (dist < bestV[a]) {
                    bestV[a] = dist;
                    bestI[a] = ci;
                }
            }
        }
    }

    // cross-thread reduction over the 16 code-groups, per row
    __syncthreads();
    float* redV = Es;                    // reuse Es region (8448 floats >= 4096 needed)
    int* redI = (int*)(Es + TM * 16);
#pragma unroll
    for (int a = 0; a < 8; ++a) {
        redV[(tr * 8 + a) * 16 + tc] = bestV[a];
        redI[(tr * 8 + a) * 16 + tc] = bestI[a];
    }
    __syncthreads();
    if (tid < TM) {
        float bv = redV[tid * 16];
        int bi = redI[tid * 16];
#pragma unroll
        for (int c = 1; c < 16; ++c) {
            float v = redV[tid * 16 + c];
            int ii = redI[tid * 16 + c];
            if (v < bv || (v == bv && ii < bi)) {
                bv = v;
                bi = ii;
            }
        }
        partial[(size_t)(row0 + tid) * SPLITK + kz] = make_float2(bv, __int_as_float(bi));
    }
}

// --- kernel 3: combine split-k partials, gather codebook row, write outputs ---
__global__ __launch_bounds__(256) void finalize_kernel(const float2* __restrict__ partial,
                                                       const float* __restrict__ x,
                                                       const float* __restrict__ cb,
                                                       float* __restrict__ out) {
    int t = blockIdx.x * 256 + threadIdx.x;  // [0, N_ROWS*4), exact
    int r = t >> 2, j = t & 3;
    float2 p = partial[(size_t)r * SPLITK];
    float bv = p.x;
    int bi = __float_as_int(p.y);
#pragma unroll
    for (int k = 1; k < SPLITK; ++k) {
        float2 q = partial[(size_t)r * SPLITK + k];
        int qi = __float_as_int(q.y);
        if (q.x < bv || (q.x == bv && qi < bi)) {
            bv = q.x;
            bi = qi;
        }
    }
    // x_q_st = x + (x_q - x), replicated with numpy's rounding
    const float4* xs = (const float4*)(x + (size_t)r * DDIM);
    const float4* qs = (const float4*)(cb + (size_t)bi * DDIM);
    float4* os = (float4*)(out + (size_t)r * DDIM);
#pragma unroll
    for (int i = 0; i < 4; ++i) {
        float4 xv = xs[j * 4 + i];
        float4 qv = qs[j * 4 + i];
        float4 ov;
        ov.x = xv.x + (qv.x - xv.x);
        ov.y = xv.y + (qv.y - xv.y);
        ov.z = xv.z + (qv.z - xv.z);
        ov.w = xv.w + (qv.w - xv.w);
        os[j * 4 + i] = ov;
    }
    if (j == 0) out[(size_t)N_ROWS * DDIM + r] = (float)bi;  // indices as float32
}

extern "C" void kernel_launch(void* const* d_in, const int* in_sizes, int n_in,
                              void* d_out, int out_size, void* d_ws, size_t ws_size,
                              hipStream_t stream) {
    const float* x = (const float*)d_in[0];    // [32768, 64]
    const float* cb = (const float*)d_in[1];   // [8192, 64]
    float* out = (float*)d_out;
    float* ws = (float*)d_ws;

    float* e2 = ws;
    float* x2 = ws + KCODES;
    float2* partial = (float2*)(ws + KCODES + N_ROWS);

    sumsq_kernel<<<(KCODES + N_ROWS) / 256, 256, 0, stream>>>(x, cb, ws);

    dim3 grid(N_ROWS / TM, SPLITK);
    dist_argmin_kernel<<<grid, 256, 0, stream>>>(x, cb, e2, x2, partial);

    finalize_kernel<<<(N_ROWS * 4) / 256, 256, 0, stream>>>(partial, x, cb, out);
}

// Round 2
// 419.553 us; speedup vs baseline: 1.1758x; 1.1758x over previous
//
#include <hip/hip_runtime.h>
#include <hip/hip_bf16.h>
#include <math.h>

// Problem constants (B=16, T=2048, D=64, K=8192)
#define N_ROWS 32768
#define KCODES 8192
#define DDIM 64

typedef __attribute__((ext_vector_type(8))) short bf16x8;
typedef __attribute__((ext_vector_type(4))) float f32x4;

// ===================== FAST PATH =====================
// ws layout (bytes):
//   o_xbf   = 0                  : x_bf   N*64 bf16   (4 MB)
//   o_cbbf  = 4194304            : cb_bf  K*64 bf16   (1 MB)
//   o_x2    = 5242880            : x2     N f32
//   o_e2    = 5373952            : e2     K f32
//   o_e2max = 5406720            : 1 f32 (atomicMax on int bits; 0xAA poison is int-negative -> safe init)
//   o_cnt   = 5406736            : per-row candidate counts, N i32
//   o_slots = 5537808 (pad16)    : candidates N*CAP i32 (8 MB)
#define CAP 64
#define O_XBF   0
#define O_CBBF  4194304UL
#define O_X2    5242880UL
#define O_E2    5373952UL
#define O_E2MAX 5406720UL
#define O_CNT   5406736UL
#define O_SLOTS 5537808UL
#define WS_NEEDED (O_SLOTS + (size_t)N_ROWS * CAP * 4)

__device__ __forceinline__ unsigned short f2bf(float f) {
    __hip_bfloat16 h = __float2bfloat16(f);  // RNE
    union { __hip_bfloat16 b; unsigned short u; } u;
    u.b = h;
    return u.u;
}

// prep: bf16 conversion + numpy-pairwise sumsq + e2max + zero counters
__global__ __launch_bounds__(256) void prep_kernel(const float* __restrict__ x,
                                                   const float* __restrict__ cb,
                                                   unsigned short* __restrict__ xbf,
                                                   unsigned short* __restrict__ cbbf,
                                                   float* __restrict__ x2,
                                                   float* __restrict__ e2,
                                                   int* __restrict__ e2max_bits,
                                                   int* __restrict__ cnt) {
#pragma clang fp contract(off)
    int t = blockIdx.x * 256 + threadIdx.x;  // exactly N_ROWS + KCODES threads
    const float* src;
    unsigned short* dstb;
    bool iscb = (t >= N_ROWS);
    int r;
    if (!iscb) {
        r = t;
        src = x + (size_t)r * DDIM;
        dstb = xbf + (size_t)r * DDIM;
        cnt[r] = 0;
    } else {
        r = t - N_ROWS;
        src = cb + (size_t)r * DDIM;
        dstb = cbbf + (size_t)r * DDIM;
    }
    // bf16 convert (vectorized)
#pragma unroll
    for (int q = 0; q < 16; ++q) {
        float4 v = ((const float4*)src)[q];
        ushort4 h;
        h.x = f2bf(v.x); h.y = f2bf(v.y); h.z = f2bf(v.z); h.w = f2bf(v.w);
        ((ushort4*)dstb)[q] = h;
    }
    // numpy pairwise sumsq (8 accumulators, contraction off)
    float acc[8];
#pragma unroll
    for (int j = 0; j < 8; ++j) {
        float v = src[j];
        acc[j] = v * v;
    }
#pragma unroll
    for (int i = 8; i < 64; i += 8) {
#pragma unroll
        for (int j = 0; j < 8; ++j) {
            float v = src[i + j];
            acc[j] = acc[j] + v * v;
        }
    }
    float s = ((acc[0] + acc[1]) + (acc[2] + acc[3])) + ((acc[4] + acc[5]) + (acc[6] + acc[7]));
    if (!iscb) {
        x2[r] = s;
    } else {
        e2[r] = s;
        atomicMax(e2max_bits, __float_as_int(s));  // positive floats: int-bit order == float order
    }
}

// screen: bf16 MFMA GEMM + per-row running min + candidate collection
// grid: (N/128, 4); block 256 (4 waves). Each block: 128 rows x 2048 codes.
#define KSPLIT2 4
#define KPER2 (KCODES / KSPLIT2)  // 2048
#define NT2 (KPER2 / 128)         // 16 code-tiles of 128

__global__ __launch_bounds__(256) void screen_kernel(const unsigned short* __restrict__ xbf,
                                                     const unsigned short* __restrict__ cbbf,
                                                     const float* __restrict__ x2,
                                                     const float* __restrict__ e2,
                                                     const int* __restrict__ e2max_bits,
                                                     int* __restrict__ cnt,
                                                     int* __restrict__ slots) {
    __shared__ uint4 Bsm[1024];  // 128 codes x 8 chunks(16B), XOR-swizzled -> 16 KB

    const int tid = threadIdx.x;
    const int w = tid >> 6;
    const int lane = tid & 63;
    const int l15 = lane & 15;
    const int quad = lane >> 4;
    const int row0 = blockIdx.x * 128;
    const int code0 = blockIdx.y * KPER2;

    // A fragments in registers for entire kernel: rt(2 row-tiles) x s(2 ksteps)
    bf16x8 afrag[2][2];
#pragma unroll
    for (int rt = 0; rt < 2; ++rt)
#pragma unroll
        for (int s = 0; s < 2; ++s) {
            int row = row0 + w * 32 + rt * 16 + l15;
            afrag[rt][s] = *(const bf16x8*)(xbf + (size_t)row * DDIM + s * 32 + quad * 8);
        }

    const float e2max = __int_as_float(*e2max_bits);
    float x2r[2][4], Mr[2][4], runmin[2][4];
#pragma unroll
    for (int rt = 0; rt < 2; ++rt)
#pragma unroll
        for (int reg = 0; reg < 4; ++reg) {
            int row = row0 + w * 32 + rt * 16 + quad * 4 + reg;
            float xv = x2[row];
            x2r[rt][reg] = xv;
            // rigorous bound on 2*|dist_np - dist_bf16| is 0.0314*||x||*||e||max (+eps); add slack
            Mr[rt][reg] = 0.032f * sqrtf(xv * e2max) + 0.03f;
            runmin[rt][reg] = 3.0e38f;
        }

    for (int t = 0; t < NT2; ++t) {
        __syncthreads();
        const int cbase = code0 + t * 128;
        // stage B tile, XOR-swizzled: chunk (c,h) -> slot c*8 + (h ^ (c&7))
        for (int i = tid; i < 1024; i += 256) {
            int c = i >> 3, h = i & 7;
            uint4 v = *(const uint4*)(cbbf + (size_t)(cbase + c) * DDIM + h * 8);
            Bsm[c * 8 + (h ^ (c & 7))] = v;
        }
        __syncthreads();

        float dist[2][8][4];
        const bf16x8* Bv = (const bf16x8*)Bsm;
#pragma unroll
        for (int ct = 0; ct < 8; ++ct) {
            int clocal = ct * 16 + l15;
            bf16x8 b0 = Bv[clocal * 8 + ((0 + quad) ^ (clocal & 7))];
            bf16x8 b1 = Bv[clocal * 8 + ((4 + quad) ^ (clocal & 7))];
            f32x4 z = {0.0f, 0.0f, 0.0f, 0.0f};
            f32x4 acc0 = __builtin_amdgcn_mfma_f32_16x16x32_bf16(afrag[0][0], b0, z, 0, 0, 0);
            acc0 = __builtin_amdgcn_mfma_f32_16x16x32_bf16(afrag[0][1], b1, acc0, 0, 0, 0);
            f32x4 acc1 = __builtin_amdgcn_mfma_f32_16x16x32_bf16(afrag[1][0], b0, z, 0, 0, 0);
            acc1 = __builtin_amdgcn_mfma_f32_16x16x32_bf16(afrag[1][1], b1, acc1, 0, 0, 0);
            float e2c = e2[cbase + clocal];
#pragma unroll
            for (int reg = 0; reg < 4; ++reg) {
                dist[0][ct][reg] = fmaf(-2.0f, acc0[reg], x2r[0][reg] + e2c);
                dist[1][ct][reg] = fmaf(-2.0f, acc1[reg], x2r[1][reg] + e2c);
            }
        }

        // per-row tile min (lane-local over 8 cols, then across the 16 lanes sharing the row)
#pragma unroll
        for (int rt = 0; rt < 2; ++rt)
#pragma unroll
            for (int reg = 0; reg < 4; ++reg) {
                float tmin = dist[rt][0][reg];
#pragma unroll
                for (int ct = 1; ct < 8; ++ct) tmin = fminf(tmin, dist[rt][ct][reg]);
                tmin = fminf(tmin, __shfl_xor(tmin, 1, 64));
                tmin = fminf(tmin, __shfl_xor(tmin, 2, 64));
                tmin = fminf(tmin, __shfl_xor(tmin, 4, 64));
                tmin = fminf(tmin, __shfl_xor(tmin, 8, 64));
                float rm = fminf(runmin[rt][reg], tmin);
                runmin[rt][reg] = rm;
                float thr = rm + Mr[rt][reg];
                int row = row0 + w * 32 + rt * 16 + quad * 4 + reg;
#pragma unroll
                for (int ct = 0; ct < 8; ++ct) {
                    if (dist[rt][ct][reg] <= thr) {
                        int code = cbase + ct * 16 + l15;
                        int pos = atomicAdd(&cnt[row], 1);
                        if (pos < CAP) slots[(size_t)row * CAP + pos] = code;
                    }
                }
            }
    }
}

// finalize: exact fp32 re-evaluation of candidates (numpy-order arithmetic), outputs
__global__ __launch_bounds__(256) void finalize2_kernel(const float* __restrict__ x,
                                                        const float* __restrict__ cb,
                                                        const float* __restrict__ x2,
                                                        const float* __restrict__ e2,
                                                        const int* __restrict__ cnt,
                                                        const int* __restrict__ slots,
                                                        float* __restrict__ out) {
    __shared__ float bvs[256];
    __shared__ int bis[256];
    int t = blockIdx.x * 256 + threadIdx.x;  // N_ROWS*4 threads
    int r = t >> 2, j = t & 3;
    const int tid = threadIdx.x;

    // row of x in registers
    float xr[64];
#pragma unroll
    for (int q = 0; q < 16; ++q) {
        float4 v = ((const float4*)(x + (size_t)r * DDIM))[q];
        xr[q * 4 + 0] = v.x; xr[q * 4 + 1] = v.y; xr[q * 4 + 2] = v.z; xr[q * 4 + 3] = v.w;
    }
    float x2v = x2[r];

    float bv = 3.0e38f;
    int bi = 0x7fffffff;
    int c = cnt[r];
    if (c > 0 && c <= CAP) {
        for (int i = j; i < c; i += 4) {
            int code = slots[(size_t)r * CAP + i];
            float xe = 0.0f;
            const float4* e4 = (const float4*)(cb + (size_t)code * DDIM);
#pragma unroll
            for (int q = 0; q < 16; ++q) {
                float4 ev = e4[q];
                xe = fmaf(xr[q * 4 + 0], ev.x, xe);
                xe = fmaf(xr[q * 4 + 1], ev.y, xe);
                xe = fmaf(xr[q * 4 + 2], ev.z, xe);
                xe = fmaf(xr[q * 4 + 3], ev.w, xe);
            }
            float ts = x2v + e2[code];
            float dist = fmaf(-2.0f, xe, ts);
            if (dist < bv || (dist == bv && code < bi)) { bv = dist; bi = code; }
        }
    } else {
        // backstop: full scan (also covers c==0 / overflow / garbage e2max)
        for (int code = j; code < KCODES; code += 4) {
            float xe = 0.0f;
            const float4* e4 = (const float4*)(cb + (size_t)code * DDIM);
#pragma unroll
            for (int q = 0; q < 16; ++q) {
                float4 ev = e4[q];
                xe = fmaf(xr[q * 4 + 0], ev.x, xe);
                xe = fmaf(xr[q * 4 + 1], ev.y, xe);
                xe = fmaf(xr[q * 4 + 2], ev.z, xe);
                xe = fmaf(xr[q * 4 + 3], ev.w, xe);
            }
            float ts = x2v + e2[code];
            float dist = fmaf(-2.0f, xe, ts);
            if (dist < bv || (dist == bv && code < bi)) { bv = dist; bi = code; }
        }
    }
    bvs[tid] = bv;
    bis[tid] = bi;
    __syncthreads();
    int base = tid & ~3;
    if (j == 0) {
#pragma unroll
        for (int jj = 1; jj < 4; ++jj) {
            float v = bvs[base + jj];
            int ii = bis[base + jj];
            if (v < bv || (v == bv && ii < bi)) { bv = v; bi = ii; }
        }
        bis[base] = bi;
    }
    __syncthreads();
    int best = bis[base];

    // x_q_st = x + (q - x), same rounding as round 1 (absmax 0)
    const float4* qs = (const float4*)(cb + (size_t)best * DDIM);
    float4* os = (float4*)(out + (size_t)r * DDIM);
#pragma unroll
    for (int i = 0; i < 4; ++i) {
        float4 qv = qs[j * 4 + i];
        float xv0 = xr[(j * 4 + i) * 4 + 0], xv1 = xr[(j * 4 + i) * 4 + 1];
        float xv2 = xr[(j * 4 + i) * 4 + 2], xv3 = xr[(j * 4 + i) * 4 + 3];
        float4 ov;
        ov.x = xv0 + (qv.x - xv0);
        ov.y = xv1 + (qv.y - xv1);
        ov.z = xv2 + (qv.z - xv2);
        ov.w = xv3 + (qv.w - xv3);
        os[j * 4 + i] = ov;
    }
    if (j == 0) out[(size_t)N_ROWS * DDIM + r] = (float)best;
}

// ===================== FALLBACK PATH (round-1, correct at 493 us) =====================
#define SPLITK 4
#define KPER (KCODES / SPLITK)
#define TM 128
#define TKT 128
#define NTILES (KPER / TKT)
#define LDSX 132
#define LDSE 132

__global__ __launch_bounds__(256) void sumsq_kernel(const float* __restrict__ x,
                                                    const float* __restrict__ cb,
                                                    float* __restrict__ ws) {
#pragma clang fp contract(off)
    int t = blockIdx.x * 256 + threadIdx.x;
    const float* src;
    float* dst;
    if (t < KCODES) { src = cb + (size_t)t * DDIM; dst = ws + t; }
    else { int r = t - KCODES; src = x + (size_t)r * DDIM; dst = ws + KCODES + r; }
    float acc[8];
#pragma unroll
    for (int j = 0; j < 8; ++j) { float v = src[j]; acc[j] = v * v; }
#pragma unroll
    for (int i = 8; i < 64; i += 8)
#pragma unroll
        for (int j = 0; j < 8; ++j) { float v = src[i + j]; acc[j] = acc[j] + v * v; }
    *dst = ((acc[0] + acc[1]) + (acc[2] + acc[3])) + ((acc[4] + acc[5]) + (acc[6] + acc[7]));
}

__global__ __launch_bounds__(256) void dist_argmin_kernel(const float* __restrict__ x,
                                                          const float* __restrict__ cb,
                                                          const float* __restrict__ e2g,
                                                          const float* __restrict__ x2g,
                                                          float2* __restrict__ partial) {
    __shared__ float smem[DDIM * LDSX + DDIM * LDSE];
    float* Xs = smem;
    float* Es = smem + DDIM * LDSX;
    const int tid = threadIdx.x;
    const int row0 = blockIdx.x * TM;
    const int code0 = blockIdx.y * KPER;
    const int tr = tid >> 4, tc = tid & 15;
    for (int i = tid; i < TM * 16; i += 256) {
        int r = i >> 4, q = i & 15;
        float4 v = ((const float4*)(x + (size_t)(row0 + r) * DDIM))[q];
        Xs[(4 * q + 0) * LDSX + r] = v.x; Xs[(4 * q + 1) * LDSX + r] = v.y;
        Xs[(4 * q + 2) * LDSX + r] = v.z; Xs[(4 * q + 3) * LDSX + r] = v.w;
    }
    float x2v[8];
#pragma unroll
    for (int j = 0; j < 8; ++j) x2v[j] = x2g[row0 + tr * 8 + j];
    float bestV[8]; int bestI[8];
#pragma unroll
    for (int j = 0; j < 8; ++j) { bestV[j] = 3.0e38f; bestI[j] = 0; }
    for (int t = 0; t < NTILES; ++t) {
        __syncthreads();
        const int cbase = code0 + t * TKT;
        for (int i = tid; i < TKT * 16; i += 256) {
            int c = i >> 4, q = i & 15;
            float4 v = ((const float4*)(cb + (size_t)(cbase + c) * DDIM))[q];
            Es[(4 * q + 0) * LDSE + c] = v.x; Es[(4 * q + 1) * LDSE + c] = v.y;
            Es[(4 * q + 2) * LDSE + c] = v.z; Es[(4 * q + 3) * LDSE + c] = v.w;
        }
        __syncthreads();
        float acc[8][8];
#pragma unroll
        for (int a = 0; a < 8; ++a)
#pragma unroll
            for (int b = 0; b < 8; ++b) acc[a][b] = 0.0f;
#pragma unroll 4
        for (int d = 0; d < DDIM; ++d) {
            float xv[8], ev[8];
            float4 xa = *(const float4*)&Xs[d * LDSX + tr * 8];
            float4 xb = *(const float4*)&Xs[d * LDSX + tr * 8 + 4];
            float4 ea = *(const float4*)&Es[d * LDSE + tc * 8];
            float4 eb = *(const float4*)&Es[d * LDSE + tc * 8 + 4];
            xv[0] = xa.x; xv[1] = xa.y; xv[2] = xa.z; xv[3] = xa.w;
            xv[4] = xb.x; xv[5] = xb.y; xv[6] = xb.z; xv[7] = xb.w;
            ev[0] = ea.x; ev[1] = ea.y; ev[2] = ea.z; ev[3] = ea.w;
            ev[4] = eb.x; ev[5] = eb.y; ev[6] = eb.z; ev[7] = eb.w;
#pragma unroll
            for (int a = 0; a < 8; ++a)
#pragma unroll
                for (int b = 0; b < 8; ++b) acc[a][b] = fmaf(xv[a], ev[b], acc[a][b]);
        }
#pragma unroll
        for (int b = 0; b < 8; ++b) {
            int ci = cbase + tc * 8 + b;
            float e2 = e2g[ci];
#pragma unroll
            for (int a = 0; a < 8; ++a) {
                float ts = x2v[a] + e2;
                float dist = fmaf(-2.0f, acc[a][b], ts);
                if (dist < bestV[a]) { bestV[a] = dist; bestI[a] = ci; }
            }
        }
    }
    __syncthreads();
    float* redV = Es;
    int* redI = (int*)(Es + TM * 16);
#pragma unroll
    for (int a = 0; a < 8; ++a) {
        redV[(tr * 8 + a) * 16 + tc] = bestV[a];
        redI[(tr * 8 + a) * 16 + tc] = bestI[a];
    }
    __syncthreads();
    if (tid < TM) {
        float bv = redV[tid * 16];
        int bi = redI[tid * 16];
#pragma unroll
        for (int c = 1; c < 16; ++c) {
            float v = redV[tid * 16 + c];
            int ii = redI[tid * 16 + c];
            if (v < bv || (v == bv && ii < bi)) { bv = v; bi = ii; }
        }
        partial[(size_t)(row0 + tid) * SPLITK + blockIdx.y] = make_float2(bv, __int_as_float(bi));
    }
}

__global__ __launch_bounds__(256) void finalize_kernel(const float2* __restrict__ partial,
                                                       const float* __restrict__ x,
                                                       const float* __restrict__ cb,
                                                       float* __restrict__ out) {
    int t = blockIdx.x * 256 + threadIdx.x;
    int r = t >> 2, j = t & 3;
    float2 p = partial[(size_t)r * SPLITK];
    float bv = p.x;
    int bi = __float_as_int(p.y);
#pragma unroll
    for (int k = 1; k < SPLITK; ++k) {
        float2 q = partial[(size_t)r * SPLITK + k];
        int qi = __float_as_int(q.y);
        if (q.x < bv || (q.x == bv && qi < bi)) { bv = q.x; bi = qi; }
    }
    const float4* xs = (const float4*)(x + (size_t)r * DDIM);
    const float4* qs = (const float4*)(cb + (size_t)bi * DDIM);
    float4* os = (float4*)(out + (size_t)r * DDIM);
#pragma unroll
    for (int i = 0; i < 4; ++i) {
        float4 xv = xs[j * 4 + i];
        float4 qv = qs[j * 4 + i];
        float4 ov;
        ov.x = xv.x + (qv.x - xv.x); ov.y = xv.y + (qv.y - xv.y);
        ov.z = xv.z + (qv.z - xv.z); ov.w = xv.w + (qv.w - xv.w);
        os[j * 4 + i] = ov;
    }
    if (j == 0) out[(size_t)N_ROWS * DDIM + r] = (float)bi;
}

// ===================== LAUNCH =====================
extern "C" void kernel_launch(void* const* d_in, const int* in_sizes, int n_in,
                              void* d_out, int out_size, void* d_ws, size_t ws_size,
                              hipStream_t stream) {
    const float* x = (const float*)d_in[0];
    const float* cb = (const float*)d_in[1];
    float* out = (float*)d_out;

    if (ws_size >= WS_NEEDED) {
        unsigned char* ws = (unsigned char*)d_ws;
        unsigned short* xbf = (unsigned short*)(ws + O_XBF);
        unsigned short* cbbf = (unsigned short*)(ws + O_CBBF);
        float* x2 = (float*)(ws + O_X2);
        float* e2 = (float*)(ws + O_E2);
        int* e2max_bits = (int*)(ws + O_E2MAX);
        int* cnt = (int*)(ws + O_CNT);
        int* slots = (int*)(ws + O_SLOTS);

        prep_kernel<<<(N_ROWS + KCODES) / 256, 256, 0, stream>>>(x, cb, xbf, cbbf, x2, e2,
                                                                 e2max_bits, cnt);
        screen_kernel<<<dim3(N_ROWS / 128, KSPLIT2), 256, 0, stream>>>(xbf, cbbf, x2, e2,
                                                                       e2max_bits, cnt, slots);
        finalize2_kernel<<<(N_ROWS * 4) / 256, 256, 0, stream>>>(x, cb, x2, e2, cnt, slots, out);
    } else {
        float* ws = (float*)d_ws;
        float* e2 = ws;
        float* x2 = ws + KCODES;
        float2* partial = (float2*)(ws + KCODES + N_ROWS);
        sumsq_kernel<<<(KCODES + N_ROWS) / 256, 256, 0, stream>>>(x, cb, ws);
        dim3 grid(N_ROWS / TM, SPLITK);
        dist_argmin_kernel<<<grid, 256, 0, stream>>>(x, cb, e2, x2, partial);
        finalize_kernel<<<(N_ROWS * 4) / 256, 256, 0, stream>>>(partial, x, cb, out);
    }
}